// Round 7
// baseline (199.170 us; speedup 1.0000x reference)
//
#include <hip/hip_runtime.h>

// GHM-C loss, single pass + tiny reduce.
// loss = sum_b S_b / (count_b * n_nonempty) over nonempty bins b.
//
// R1: same-address device atomics = 1.2 ms cross-XCD bouncing -> per-block partials.
// R2: 10-way register binning ~50 VALU instr/elem -> LDS private hist.
// R3: latency convoy (VGPR=32, ~2 KB/wave in flight) -> need prefetch distance.
// R4: runtime-indexed buffers -> scratch spill (165 MB writes). Proved mem system
//     sustains 3.4 TB/s here -> 1.2 TB/s is not a ceiling.
// R5: compiler re-sank statically-indexed prefetch (VGPR back to 32).
// R6: tied "+v"(float4) waitcnt operands -> backend error (tied indirect regs).
//     This round: operand-free s_waitcnt asm pinned by sched_barrier(0) fences
//     (mask 0 = no instruction may cross; respected pre- and post-RA).

#define NBINS  10
#define GRID1  2048
#define BLOCK1 256

__device__ __forceinline__ float4 gload_f4(const float4* p) {
    float4 r;
    asm volatile("global_load_dwordx4 %0, %1, off" : "=v"(r) : "v"(p));
    return r;
}
__device__ __forceinline__ int4 gload_i4(const int4* p) {
    int4 r;
    asm volatile("global_load_dwordx4 %0, %1, off" : "=v"(r) : "v"(p));
    return r;
}

__device__ __forceinline__ void ghmc_elem(float x, int t, float* hist, int tid,
                                          unsigned long long& cnt)
{
    float tf = (float)t;
    float z  = __builtin_amdgcn_rcpf(1.0f + __expf(-x));   // sigmoid
    float g  = fabsf(z - tf);
    int   bi = (int)(g * 10.0f);
    bi = bi > (NBINS - 1) ? (NBINS - 1) : bi;
    float bce = __logf(1.0f + __expf(z)) - tf * z;         // softplus(z) - t*z
    hist[bi * BLOCK1 + tid] += bce;                        // bank = tid%32 always: free
    cnt += 1ull << (6 * bi);                               // 10x6-bit packed counts
}

__device__ __forceinline__ void ghmc_epilogue(float* hist, unsigned long long cnt,
                                              float* partial_s, int* partial_c,
                                              float (*sred)[NBINS], int (*cred)[NBINS])
{
    const int tid = threadIdx.x;
    float s[NBINS];
    int   c[NBINS];
#pragma unroll
    for (int b = 0; b < NBINS; ++b) {
        s[b] = hist[b * BLOCK1 + tid];
        c[b] = (int)((cnt >> (6 * b)) & 63ull);
    }
#pragma unroll
    for (int b = 0; b < NBINS; ++b) {
#pragma unroll
        for (int off = 32; off > 0; off >>= 1) {
            s[b] += __shfl_down(s[b], off, 64);
            c[b] += __shfl_down(c[b], off, 64);
        }
    }
    const int wave = tid >> 6;
    if ((tid & 63) == 0) {
#pragma unroll
        for (int b = 0; b < NBINS; ++b) { sred[wave][b] = s[b]; cred[wave][b] = c[b]; }
    }
    __syncthreads();
    if (tid < NBINS) {
        int b = tid;
        partial_s[b * GRID1 + blockIdx.x] = sred[0][b] + sred[1][b] + sred[2][b] + sred[3][b];
        partial_c[b * GRID1 + blockIdx.x] = cred[0][b] + cred[1][b] + cred[2][b] + cred[3][b];
    }
}

// Specialized: TRIPS=10, all 20 loads issued up-front via volatile asm,
// two-phase consume gated by manual vmcnt waits pinned with sched_barrier(0).
__global__ __launch_bounds__(BLOCK1, 2) void ghmc_pass1_t10(
    const float4* __restrict__ pred4,
    const int4*   __restrict__ targ4,
    float* __restrict__ partial_s,   // [NBINS][GRID1] bin-major
    int*   __restrict__ partial_c)
{
    constexpr int HALF = 5;
    __shared__ float hist[NBINS * BLOCK1];
    __shared__ float sred[BLOCK1 / 64][NBINS];
    __shared__ int   cred[BLOCK1 / 64][NBINS];

    const int tid = threadIdx.x;
#pragma unroll
    for (int b = 0; b < NBINS; ++b) hist[b * BLOCK1 + tid] = 0.0f;
    // no barrier: each thread only touches its own slots

    unsigned long long cnt = 0;
    const int i0     = blockIdx.x * BLOCK1 + tid;
    const int stride = GRID1 * BLOCK1;

    float4 PA[HALF], PB[HALF];
    int4   TA[HALF], TB[HALF];

    // Issue ALL 20 loads in order. Volatile asms keep mutual program order:
    // A batch occupies vmcnt slots 19..10 (oldest), B batch 9..0.
#pragma unroll
    for (int j = 0; j < HALF; ++j) {
        PA[j] = gload_f4(&pred4[i0 + j * stride]);
        TA[j] = gload_i4(&targ4[i0 + j * stride]);
    }
#pragma unroll
    for (int j = 0; j < HALF; ++j) {
        PB[j] = gload_f4(&pred4[i0 + (HALF + j) * stride]);
        TB[j] = gload_i4(&targ4[i0 + (HALF + j) * stride]);
    }

    // Wait for A batch only (<=10 outstanding left = B may still be in flight).
    __builtin_amdgcn_sched_barrier(0);
    asm volatile("s_waitcnt vmcnt(10)" ::: "memory");
    __builtin_amdgcn_sched_barrier(0);

#pragma unroll
    for (int j = 0; j < HALF; ++j) {
        ghmc_elem(PA[j].x, TA[j].x, hist, tid, cnt);
        ghmc_elem(PA[j].y, TA[j].y, hist, tid, cnt);
        ghmc_elem(PA[j].z, TA[j].z, hist, tid, cnt);
        ghmc_elem(PA[j].w, TA[j].w, hist, tid, cnt);
    }

    // Drain B batch, then consume it.
    __builtin_amdgcn_sched_barrier(0);
    asm volatile("s_waitcnt vmcnt(0)" ::: "memory");
    __builtin_amdgcn_sched_barrier(0);

#pragma unroll
    for (int j = 0; j < HALF; ++j) {
        ghmc_elem(PB[j].x, TB[j].x, hist, tid, cnt);
        ghmc_elem(PB[j].y, TB[j].y, hist, tid, cnt);
        ghmc_elem(PB[j].z, TB[j].z, hist, tid, cnt);
        ghmc_elem(PB[j].w, TB[j].w, hist, tid, cnt);
    }

    ghmc_epilogue(hist, cnt, partial_s, partial_c, sred, cred);
}

// Generic fallback for any size (simple grid-stride loop, correctness-first).
__global__ __launch_bounds__(BLOCK1) void ghmc_pass1_gen(
    const float4* __restrict__ pred4,
    const int4*   __restrict__ targ4,
    float* __restrict__ partial_s,
    int*   __restrict__ partial_c,
    int nvec4)
{
    __shared__ float hist[NBINS * BLOCK1];
    __shared__ float sred[BLOCK1 / 64][NBINS];
    __shared__ int   cred[BLOCK1 / 64][NBINS];

    const int tid = threadIdx.x;
#pragma unroll
    for (int b = 0; b < NBINS; ++b) hist[b * BLOCK1 + tid] = 0.0f;

    unsigned long long cnt = 0;
    const int i0     = blockIdx.x * BLOCK1 + tid;
    const int stride = GRID1 * BLOCK1;

    for (int i = i0; i < nvec4; i += stride) {
        float4 p = pred4[i];
        int4   t = targ4[i];
        ghmc_elem(p.x, t.x, hist, tid, cnt);
        ghmc_elem(p.y, t.y, hist, tid, cnt);
        ghmc_elem(p.z, t.z, hist, tid, cnt);
        ghmc_elem(p.w, t.w, hist, tid, cnt);
    }

    ghmc_epilogue(hist, cnt, partial_s, partial_c, sred, cred);
}

__global__ __launch_bounds__(256) void ghmc_pass2(
    const float* __restrict__ partial_s,   // [NBINS][GRID1]
    const int*   __restrict__ partial_c,
    float* __restrict__ out,
    int nblocks)
{
    double as[NBINS];
    int    ac[NBINS];
#pragma unroll
    for (int b = 0; b < NBINS; ++b) { as[b] = 0.0; ac[b] = 0; }

    for (int j = threadIdx.x; j < nblocks; j += 256) {
#pragma unroll
        for (int b = 0; b < NBINS; ++b) {
            as[b] += (double)partial_s[b * nblocks + j];   // coalesced per bin
            ac[b] += partial_c[b * nblocks + j];
        }
    }

#pragma unroll
    for (int b = 0; b < NBINS; ++b) {
#pragma unroll
        for (int off = 32; off > 0; off >>= 1) {
            as[b] += __shfl_down(as[b], off, 64);
            ac[b] += __shfl_down(ac[b], off, 64);
        }
    }

    __shared__ double sds[4][NBINS];
    __shared__ int    sdc[4][NBINS];
    int wave = threadIdx.x >> 6;
    if ((threadIdx.x & 63) == 0) {
#pragma unroll
        for (int b = 0; b < NBINS; ++b) { sds[wave][b] = as[b]; sdc[wave][b] = ac[b]; }
    }
    __syncthreads();

    if (threadIdx.x == 0) {
        int nn = 0;
        double acc = 0.0;
#pragma unroll
        for (int b = 0; b < NBINS; ++b) {
            double sb = sds[0][b] + sds[1][b] + sds[2][b] + sds[3][b];
            int    cb = sdc[0][b] + sdc[1][b] + sdc[2][b] + sdc[3][b];
            if (cb > 0) { nn += 1; acc += sb / (double)cb; }
        }
        out[0] = (float)(acc / (double)(nn > 0 ? nn : 1));
    }
}

extern "C" void kernel_launch(void* const* d_in, const int* in_sizes, int n_in,
                              void* d_out, int out_size, void* d_ws, size_t ws_size,
                              hipStream_t stream)
{
    const float* pred = (const float*)d_in[0];
    const int*   targ = (const int*)d_in[1];
    float*       out  = (float*)d_out;

    const int n     = in_sizes[0];   // 20,971,520
    const int nvec4 = n / 4;         // 5,242,880 = 10 * (2048*256) exactly

    float* partial_s = (float*)d_ws;                                  // NBINS*GRID1 floats
    int*   partial_c = (int*)((char*)d_ws + GRID1 * NBINS * sizeof(float));

    const int stride = GRID1 * BLOCK1;
    if (nvec4 == 10 * stride) {
        ghmc_pass1_t10<<<GRID1, BLOCK1, 0, stream>>>(
            (const float4*)pred, (const int4*)targ, partial_s, partial_c);
    } else {
        ghmc_pass1_gen<<<GRID1, BLOCK1, 0, stream>>>(
            (const float4*)pred, (const int4*)targ, partial_s, partial_c, nvec4);
    }

    ghmc_pass2<<<1, 256, 0, stream>>>(partial_s, partial_c, out, GRID1);
}